// Round 1
// 236.593 us; speedup vs baseline: 1.2631x; 1.2631x over previous
//
#include <hip/hip_runtime.h>
#include <hip/hip_bf16.h>

#define N_NODES 262144
#define C_CH 64
#define K_NBR 16
#define NCLS 40
#define GPB 4   // groups (of 64 nodes) per block in the dense head kernel

typedef unsigned short ushort_t;
typedef __attribute__((ext_vector_type(8))) short short8;
typedef __attribute__((ext_vector_type(4))) float floatx4;

__device__ __forceinline__ float bu2f(ushort_t u) {
    union { unsigned u32; float f; } v; v.u32 = ((unsigned)u) << 16; return v.f;
}
__device__ __forceinline__ ushort_t f2bu(float f) {
    union { float f; unsigned u; } v; v.f = f;
    unsigned r = v.u + 0x7FFFu + ((v.u >> 16) & 1u);
    return (ushort_t)(r >> 16);
}
__device__ __forceinline__ floatx4 bcast4(float g) {
    floatx4 v; v[0] = g; v[1] = g; v[2] = g; v[3] = g; return v;
}
__device__ __forceinline__ int ldi(const int* p, long i)       { return p[i]; }
__device__ __forceinline__ int ldi(const long long* p, long i) { return (int)p[i]; }

// ---------------- Sniffer: flags[1] = 1 if nbr is int64 ----------------------
__global__ void sniff_kernel(const void* __restrict__ nbr, int* __restrict__ flags) {
    int lane = threadIdx.x;                 // 64 threads
    const int* ni = (const int*)nbr;
    bool zodd = (ni[2 * lane + 1] == 0);    // int64 high words all zero
    unsigned long long mz = __ballot(zodd);
    if (lane == 0) flags[1] = (mz == ~0ULL) ? 1 : 0;
}

// ---------------- Kernel A: CPE depthwise conv3 + residual ------------------
// f32 x -> bf16 h table. One thread = 4 channels (float4) x 4 nodes.
__global__ void cpe_kernel(const float* __restrict__ x,
                           const float* __restrict__ cw,
                           const float* __restrict__ cb,
                           ushort_t* __restrict__ h) {
    int t  = blockIdx.x * 256 + threadIdx.x;   // [0, N/4 * 16)
    int ig = t >> 4;                           // node group (4 nodes)
    int cq = t & 15;                           // channel quad
    int i0 = ig << 2;
    int c0 = cq * 4;
    float w0[4], w1[4], w2[4], bb[4];
#pragma unroll
    for (int j = 0; j < 4; ++j) {
        w0[j] = cw[(c0 + j) * 3 + 0];
        w1[j] = cw[(c0 + j) * 3 + 1];
        w2[j] = cw[(c0 + j) * 3 + 2];
        bb[j] = cb[c0 + j];
    }
    float4 v[6];
#pragma unroll
    for (int r = 0; r < 6; ++r) {
        int i = i0 - 1 + r;
        if (i >= 0 && i < N_NODES) v[r] = *(const float4*)(x + (size_t)i * C_CH + c0);
        else                       v[r] = make_float4(0.f, 0.f, 0.f, 0.f);
    }
#pragma unroll
    for (int j = 0; j < 4; ++j) {
        float a[4] = {v[j].x, v[j].y, v[j].z, v[j].w};
        float b[4] = {v[j+1].x, v[j+1].y, v[j+1].z, v[j+1].w};
        float c[4] = {v[j+2].x, v[j+2].y, v[j+2].z, v[j+2].w};
        unsigned p0 = 0, p1 = 0;
#pragma unroll
        for (int q = 0; q < 4; ++q) {
            float r = b[q] + bb[q];
            r = fmaf(a[q], w0[q], r);
            r = fmaf(b[q], w1[q], r);
            r = fmaf(c[q], w2[q], r);
            unsigned u = (unsigned)f2bu(r);
            if (q < 2) p0 |= u << (q * 16);
            else       p1 |= u << ((q - 2) * 16);
        }
        *(uint2*)(h + (size_t)(i0 + j) * C_CH + c0) = make_uint2(p0, p1);
    }
}

// ---------------- Kernel G: standalone gather + max-rel ---------------------
// MLP-optimized: per node, all 16 row-loads issued into a register batch
// (16 outstanding per wave) before the fmax tree. One wave = 4 nodes.
template <typename IT>
__global__ void __launch_bounds__(256, 8)
gather_kernel(const int* __restrict__ flags,
              const ushort_t* __restrict__ hws,
              const IT* __restrict__ nbr,
              ushort_t* __restrict__ relws) {
    if ((flags[1] != 0) != (sizeof(IT) == 8)) return;
    const int lane = threadIdx.x & 63;
    const int wid  = (blockIdx.x * 256 + threadIdx.x) >> 6;  // global wave id
    const int nb   = wid * 4;                                // 4 nodes per wave
    const ushort_t* hl = hws + lane;                         // per-lane base
    int idxv = ldi(nbr, (long)nb * K_NBR + lane);            // 4 rows x 16 nbrs
#pragma unroll
    for (int t = 0; t < 4; ++t) {
        unsigned off[16];
#pragma unroll
        for (int k = 0; k < 16; ++k)
            off[k] = ((unsigned)__shfl(idxv, t * 16 + k, 64)) << 6;
        float v[16];
#pragma unroll
        for (int k = 0; k < 16; ++k)                 // 16 independent loads
            v[k] = bu2f(hl[(size_t)off[k]]);
#pragma unroll
        for (int s = 8; s; s >>= 1)                  // fmax tree
#pragma unroll
            for (int k = 0; k < s; ++k)
                v[k] = fmaxf(v[k], v[k + s]);
        float hv = bu2f(hl[(size_t)(unsigned)(nb + t) << 6]);
        relws[((size_t)(nb + t) << 6) + lane] = f2bu(v[0] - hv);
    }
}

// ---------------- Kernel B: MFMA proj/head + logsoftmax ---------------------
// DENSE=true: A-fragments read DIRECTLY from h/rel tables (row layout == A
// layout), no sFeat staging. Grid = NGRP/GPB blocks, each block loops GPB
// contiguous groups so the (expensive) weight staging is amortized. After
// the one staging barrier, all LDS (sH2[wave]) is strictly per-wave, so the
// intra-loop __syncthreads() are replaced by zero-cost compiler memory
// clobbers (per-wave DS ops are in-order; clobber only blocks TBAA-based
// reordering of the float*/short8* aliased sH2 reuse). Next group's
// A-fragments are prefetched before the current MFMAs to hide global latency
// under the head+softmax phase.
// DENSE=false: r10 fused fallback (small ws), unchanged semantics.
template <bool DENSE, typename IT>
__global__ void __launch_bounds__(256, 4)
graph_head_kernel(const int* __restrict__ flags,
                  const ushort_t* __restrict__ hws,
                  const ushort_t* __restrict__ relws,
                  const IT* __restrict__ nbr,
                  const float* __restrict__ gw,
                  const float* __restrict__ gb,
                  const float* __restrict__ ow,
                  const float* __restrict__ ob,
                  float* __restrict__ out) {
    if (!DENSE) { if ((flags[1] != 0) != (sizeof(IT) == 8)) return; }

    __shared__ __align__(16) ushort_t sWt[64 * 136];       // 17408 B: W'[n][k], k=0..127
    __shared__ __align__(16) ushort_t sOt[48 * 72];        //  6912 B: O[n][k],  k=0..63
    __shared__ __align__(16) ushort_t sFeat[DENSE ? 1 : 4][DENSE ? 16 : 16 * 136];
    __shared__ __align__(16) ushort_t sH2[4][16 * 88];     // 11264 B: h2 rows / logit stage
    // DENSE: ~35.6 KB -> 4 blocks/CU

    // ---- stage transposed weights (once per block) ----
    // sWt: coalesced float4 global reads (lanes cover consecutive n), 8/thread
    for (int t = threadIdx.x; t < 64 * 128 / 4; t += 256) {
        int k  = t >> 4;            // 0..127
        int n0 = (t & 15) * 4;      // 0..60
        float4 w4 = *(const float4*)(gw + k * C_CH + n0);
        float wv[4] = {w4.x, w4.y, w4.z, w4.w};
#pragma unroll
        for (int q = 0; q < 4; ++q) {
            float w = wv[q];
            if (k == n0 + q) w += 1.0f;          // residual folded in: W' = W + [I;0]
            sWt[(n0 + q) * 136 + k] = f2bu(w);
        }
    }
    for (int t = threadIdx.x; t < 48 * 64; t += 256) {
        int n = t >> 6, k = t & 63;
        float w = (n < NCLS) ? ow[k * NCLS + n] : 0.f;
        sOt[n * 72 + k] = f2bu(w);
    }
    __syncthreads();

    const int lane   = threadIdx.x & 63;
    const int wave   = threadIdx.x >> 6;
    const int lanelo = lane & 15;
    const int quad   = lane >> 4;

    float gbf[4];
#pragma unroll
    for (int nt = 0; nt < 4; ++nt) gbf[nt] = gb[nt * 16 + lanelo];
    float obf[3];
#pragma unroll
    for (int nt = 0; nt < 3; ++nt) {
        int n = nt * 16 + lanelo;
        obf[nt] = (n < NCLS) ? ob[n] : 0.f;
    }
    const bool ok2 = (lanelo < 8);   // n-tile 2 covers cols 32..47; valid n<40

    int gBeg, gEnd, gStep;
    if constexpr (DENSE) { gBeg = blockIdx.x * GPB; gEnd = gBeg + GPB; gStep = 1; }
    else                 { gBeg = blockIdx.x; gEnd = (N_NODES >> 6); gStep = gridDim.x; }

    // ---- DENSE: prefetch first group's A-fragments ----
    short8 afc[4];
    if constexpr (DENSE) {
        const int nb0 = gBeg * 64 + wave * 16;
#pragma unroll
        for (int s = 0; s < 4; ++s) {
            const ushort_t* tbl = (s < 2) ? hws : relws;
            afc[s] = *(const short8*)(tbl + ((size_t)(nb0 + lanelo) << 6)
                                      + (s & 1) * 32 + quad * 8);
        }
    }

    for (int g = gBeg; g < gEnd; g += gStep) {
        const int nb0 = g * 64 + wave * 16;
        ushort_t* h2w = &sH2[wave][0];

        // ---- proj: D[16x64] = feat[16x128] @ W' + gb ----
        floatx4 acc[4];
#pragma unroll
        for (int nt = 0; nt < 4; ++nt) acc[nt] = bcast4(gbf[nt]);

        if constexpr (DENSE) {
            // issue next group's A-frag loads FIRST: ~900cy HBM/L3 latency
            // hides under this group's MFMAs + head + softmax.
            short8 afn[4];
            const int gn  = (g + 1 < gEnd) ? g + 1 : g;   // clamp: harmless reload
            const int nbn = gn * 64 + wave * 16;
#pragma unroll
            for (int s = 0; s < 4; ++s) {
                const ushort_t* tbl = (s < 2) ? hws : relws;
                afn[s] = *(const short8*)(tbl + ((size_t)(nbn + lanelo) << 6)
                                          + (s & 1) * 32 + quad * 8);
            }
#pragma unroll
            for (int s = 0; s < 4; ++s) {
#pragma unroll
                for (int nt = 0; nt < 4; ++nt) {
                    short8 bf = *(const short8*)(sWt + (nt * 16 + lanelo) * 136 + s * 32 + quad * 8);
                    acc[nt] = __builtin_amdgcn_mfma_f32_16x16x32_bf16(afc[s], bf, acc[nt], 0, 0, 0);
                }
            }
#pragma unroll
            for (int s = 0; s < 4; ++s) afc[s] = afn[s];
        } else {
            ushort_t* feat = &sFeat[wave][0];
#pragma unroll
            for (int q = 0; q < 4; ++q) {
                int idxv = ldi(nbr, (long)nb0 * K_NBR + q * 64 + lane);
#pragma unroll
                for (int tt = 0; tt < 4; ++tt) {
                    int t = q * 4 + tt;
                    ushort_t hu = hws[(size_t)(nb0 + t) * C_CH + lane];
                    float hif = bu2f(hu);
                    float mx = -1e30f;
#pragma unroll
                    for (int k = 0; k < 16; ++k) {
                        int j = __shfl(idxv, tt * 16 + k, 64);
                        mx = fmaxf(mx, bu2f(hws[((size_t)(unsigned)j << 6) + lane]));
                    }
                    feat[t * 136 + lane]      = hu;
                    feat[t * 136 + 64 + lane] = f2bu(mx - hif);
                }
            }
            __syncthreads();
#pragma unroll
            for (int s = 0; s < 4; ++s) {
                short8 af = *(const short8*)(feat + lanelo * 136 + s * 32 + quad * 8);
#pragma unroll
                for (int nt = 0; nt < 4; ++nt) {
                    short8 bf = *(const short8*)(sWt + (nt * 16 + lanelo) * 136 + s * 32 + quad * 8);
                    acc[nt] = __builtin_amdgcn_mfma_f32_16x16x32_bf16(af, bf, acc[nt], 0, 0, 0);
                }
            }
        }

#pragma unroll
        for (int nt = 0; nt < 4; ++nt)
#pragma unroll
            for (int r = 0; r < 4; ++r)
                h2w[(quad * 4 + r) * 88 + nt * 16 + lanelo] = f2bu(acc[nt][r]);
        if constexpr (DENSE) { asm volatile("" ::: "memory"); }  // sH2 per-wave: order-only fence
        else                 { __syncthreads(); }

        // ---- head: L[16x48] = h2[16x64] @ O (+ ob) ----
        floatx4 accH[3];
#pragma unroll
        for (int nt = 0; nt < 3; ++nt) accH[nt] = bcast4(obf[nt]);
#pragma unroll
        for (int s = 0; s < 2; ++s) {
            short8 hf = *(const short8*)(h2w + lanelo * 88 + s * 32 + quad * 8);
#pragma unroll
            for (int nt = 0; nt < 3; ++nt) {
                short8 bf = *(const short8*)(sOt + (nt * 16 + lanelo) * 72 + s * 32 + quad * 8);
                accH[nt] = __builtin_amdgcn_mfma_f32_16x16x32_bf16(hf, bf, accH[nt], 0, 0, 0);
            }
        }
        if constexpr (DENSE) { asm volatile("" ::: "memory"); }  // h2 reads before fOut overwrite

        // ---- log-softmax per row; stage logits in LDS (reuse h2 region) ----
        float* fOut = (float*)h2w;
#pragma unroll
        for (int r = 0; r < 4; ++r) {
            float v0 = accH[0][r], v1 = accH[1][r];
            float v2 = ok2 ? accH[2][r] : -1e30f;
            float m = fmaxf(fmaxf(v0, v1), v2);
#pragma unroll
            for (int off = 1; off < 16; off <<= 1) m = fmaxf(m, __shfl_xor(m, off, 64));
            float s = __expf(v0 - m) + __expf(v1 - m) + (ok2 ? __expf(v2 - m) : 0.f);
#pragma unroll
            for (int off = 1; off < 16; off <<= 1) s += __shfl_xor(s, off, 64);
            float li = m + __logf(s);
            int rowbase = (quad * 4 + r) * NCLS;
            fOut[rowbase + lanelo]      = v0 - li;
            fOut[rowbase + 16 + lanelo] = v1 - li;
            if (ok2) fOut[rowbase + 32 + lanelo] = v2 - li;
        }
        if constexpr (DENSE) { asm volatile("" ::: "memory"); }  // fOut writes before readback
        else                 { __syncthreads(); }

        // ---- flat coalesced write: 640 consecutive floats per wave ----
        float* obase = out + (size_t)nb0 * NCLS;
#pragma unroll
        for (int k = 0; k < 10; ++k)
            obase[k * 64 + lane] = fOut[k * 64 + lane];
        if constexpr (DENSE) { asm volatile("" ::: "memory"); }  // fOut reads before next-iter h2 write
    }
}

extern "C" void kernel_launch(void* const* d_in, const int* in_sizes, int n_in,
                              void* d_out, int out_size, void* d_ws, size_t ws_size,
                              hipStream_t stream) {
    const float* x  = (const float*)d_in[0];
    const float* cw = (const float*)d_in[2];
    const float* cb = (const float*)d_in[3];
    const float* gw = (const float*)d_in[4];
    const float* gb = (const float*)d_in[5];
    const float* ow = (const float*)d_in[6];
    const float* ob = (const float*)d_in[7];
    float* out = (float*)d_out;

    int* flags = (int*)d_ws;
    ushort_t* hws   = (ushort_t*)((char*)d_ws + 1024);              // 32 MB
    ushort_t* relws = (ushort_t*)((char*)d_ws + 1024 + 33554432);   // 32 MB

    const bool split = (ws_size >= (size_t)(1024 + 2 * 33554432ULL));

    sniff_kernel<<<1, 64, 0, stream>>>(d_in[1], flags);
    cpe_kernel<<<(N_NODES / 4 * 16) / 256, 256, 0, stream>>>(x, cw, cb, hws);

    if (split) {
        // MLP-optimized gather: 16384 blocks, 4 nodes/wave
        gather_kernel<int><<<N_NODES / 16, 256, 0, stream>>>(
            flags, hws, (const int*)d_in[1], relws);
        gather_kernel<long long><<<N_NODES / 16, 256, 0, stream>>>(
            flags, hws, (const long long*)d_in[1], relws);
        // dense MFMA pipeline: 1024 blocks x GPB=4 groups, staging amortized
        graph_head_kernel<true, int><<<(N_NODES / 64) / GPB, 256, 0, stream>>>(
            flags, hws, relws, (const int*)d_in[1], gw, gb, ow, ob, out);
    } else {
        // fallback: fused gather (round-10 path)
        graph_head_kernel<false, int><<<2048, 256, 0, stream>>>(
            flags, hws, relws, (const int*)d_in[1], gw, gb, ow, ob, out);
        graph_head_kernel<false, long long><<<2048, 256, 0, stream>>>(
            flags, hws, relws, (const long long*)d_in[1], gw, gb, ow, ob, out);
    }
}

// Round 2
// 234.954 us; speedup vs baseline: 1.2719x; 1.0070x over previous
//
#include <hip/hip_runtime.h>
#include <hip/hip_bf16.h>

#define N_NODES 262144
#define C_CH 64
#define K_NBR 16
#define NCLS 40
#define GPB 4   // groups (of 64 nodes) per block in the dense head kernel

typedef unsigned short ushort_t;
typedef __attribute__((ext_vector_type(8))) short short8;
typedef __attribute__((ext_vector_type(4))) float floatx4;

__device__ __forceinline__ float bu2f(ushort_t u) {
    union { unsigned u32; float f; } v; v.u32 = ((unsigned)u) << 16; return v.f;
}
__device__ __forceinline__ ushort_t f2bu(float f) {
    union { float f; unsigned u; } v; v.f = f;
    unsigned r = v.u + 0x7FFFu + ((v.u >> 16) & 1u);
    return (ushort_t)(r >> 16);
}
__device__ __forceinline__ floatx4 bcast4(float g) {
    floatx4 v; v[0] = g; v[1] = g; v[2] = g; v[3] = g; return v;
}
__device__ __forceinline__ int ldi(const int* p, long i)       { return p[i]; }
__device__ __forceinline__ int ldi(const long long* p, long i) { return (int)p[i]; }

// ---------------- Sniffer: flags[1] = 1 if nbr is int64 ----------------------
__global__ void sniff_kernel(const void* __restrict__ nbr, int* __restrict__ flags) {
    int lane = threadIdx.x;                 // 64 threads
    const int* ni = (const int*)nbr;
    bool zodd = (ni[2 * lane + 1] == 0);    // int64 high words all zero
    unsigned long long mz = __ballot(zodd);
    if (lane == 0) flags[1] = (mz == ~0ULL) ? 1 : 0;
}

// ---------------- Kernel A: CPE depthwise conv3 + residual ------------------
// f32 x -> bf16 h table. One thread = 4 channels (float4) x 4 nodes.
__global__ void cpe_kernel(const float* __restrict__ x,
                           const float* __restrict__ cw,
                           const float* __restrict__ cb,
                           ushort_t* __restrict__ h) {
    int t  = blockIdx.x * 256 + threadIdx.x;   // [0, N/4 * 16)
    int ig = t >> 4;                           // node group (4 nodes)
    int cq = t & 15;                           // channel quad
    int i0 = ig << 2;
    int c0 = cq * 4;
    float w0[4], w1[4], w2[4], bb[4];
#pragma unroll
    for (int j = 0; j < 4; ++j) {
        w0[j] = cw[(c0 + j) * 3 + 0];
        w1[j] = cw[(c0 + j) * 3 + 1];
        w2[j] = cw[(c0 + j) * 3 + 2];
        bb[j] = cb[c0 + j];
    }
    float4 v[6];
#pragma unroll
    for (int r = 0; r < 6; ++r) {
        int i = i0 - 1 + r;
        if (i >= 0 && i < N_NODES) v[r] = *(const float4*)(x + (size_t)i * C_CH + c0);
        else                       v[r] = make_float4(0.f, 0.f, 0.f, 0.f);
    }
#pragma unroll
    for (int j = 0; j < 4; ++j) {
        float a[4] = {v[j].x, v[j].y, v[j].z, v[j].w};
        float b[4] = {v[j+1].x, v[j+1].y, v[j+1].z, v[j+1].w};
        float c[4] = {v[j+2].x, v[j+2].y, v[j+2].z, v[j+2].w};
        unsigned p0 = 0, p1 = 0;
#pragma unroll
        for (int q = 0; q < 4; ++q) {
            float r = b[q] + bb[q];
            r = fmaf(a[q], w0[q], r);
            r = fmaf(b[q], w1[q], r);
            r = fmaf(c[q], w2[q], r);
            unsigned u = (unsigned)f2bu(r);
            if (q < 2) p0 |= u << (q * 16);
            else       p1 |= u << ((q - 2) * 16);
        }
        *(uint2*)(h + (size_t)(i0 + j) * C_CH + c0) = make_uint2(p0, p1);
    }
}

// ---------------- Kernel G: standalone gather + max-rel ---------------------
// Scalar-index version: neighbor indices for a wave's 4 nodes are the 64
// CONTIGUOUS entries nbr[nb*16 .. +64); forcing the wave id uniform via
// readfirstlane turns the index loads into s_load_dwordx16 batches (scalar
// pipe, overlaps VALU) and each row gather into global_load_ushort with an
// SGPR row base + constant per-lane voffset. This removes all 64
// ds_bpermute broadcasts and their lgkmcnt stalls per wave, shortening the
// address-dependence chain ahead of the 16-deep load batches.
template <typename IT>
__device__ __forceinline__ void gather_body(const ushort_t* __restrict__ hws,
                                            const IT* __restrict__ nbr,
                                            ushort_t* __restrict__ relws,
                                            int lane, int wid) {
    const int nb = wid * 4;                                  // 4 nodes per wave
    const ushort_t* hl = hws + lane;                         // per-lane base
    const IT* nrow = nbr + (size_t)nb * K_NBR;               // wave-uniform ptr
#pragma unroll
    for (int t = 0; t < 4; ++t) {
        float v[16];
#pragma unroll
        for (int k = 0; k < 16; ++k) {
            int idx = (int)nrow[t * 16 + k];                 // uniform -> s_load
            v[k] = bu2f(hl[(size_t)(unsigned)idx << 6]);     // SGPR base + lane
        }
#pragma unroll
        for (int s = 8; s; s >>= 1)                          // fmax tree
#pragma unroll
            for (int k = 0; k < s; ++k)
                v[k] = fmaxf(v[k], v[k + s]);
        float hv = bu2f(hl[(size_t)(unsigned)(nb + t) << 6]);
        relws[((size_t)(nb + t) << 6) + lane] = f2bu(v[0] - hv);
    }
}

__global__ void __launch_bounds__(256, 8)
gather_kernel(const int* __restrict__ flags,
              const ushort_t* __restrict__ hws,
              const void* __restrict__ nbr,
              ushort_t* __restrict__ relws) {
    const int lane = threadIdx.x & 63;
    int wid = (blockIdx.x * 256 + threadIdx.x) >> 6;         // global wave id
    wid = __builtin_amdgcn_readfirstlane(wid);               // force SGPR
    if (flags[1]) gather_body<long long>(hws, (const long long*)nbr, relws, lane, wid);
    else          gather_body<int>(hws, (const int*)nbr, relws, lane, wid);
}

// ---------------- Kernel B: MFMA proj/head + logsoftmax ---------------------
// DENSE=true: A-fragments read DIRECTLY from h/rel tables (row layout == A
// layout), no sFeat staging. Grid = NGRP/GPB blocks, each block loops GPB
// contiguous groups so the (expensive) weight staging is amortized. After
// the one staging barrier, all LDS (sH2[wave]) is strictly per-wave, so the
// intra-loop __syncthreads() are replaced by zero-cost compiler memory
// clobbers. Next group's A-fragments are prefetched before the current MFMAs
// to hide global latency under the head+softmax phase.
// DENSE=false: r10 fused fallback (small ws), unchanged semantics.
template <bool DENSE, typename IT>
__global__ void __launch_bounds__(256, 4)
graph_head_kernel(const int* __restrict__ flags,
                  const ushort_t* __restrict__ hws,
                  const ushort_t* __restrict__ relws,
                  const IT* __restrict__ nbr,
                  const float* __restrict__ gw,
                  const float* __restrict__ gb,
                  const float* __restrict__ ow,
                  const float* __restrict__ ob,
                  float* __restrict__ out) {
    if (!DENSE) { if ((flags[1] != 0) != (sizeof(IT) == 8)) return; }

    __shared__ __align__(16) ushort_t sWt[64 * 136];       // 17408 B: W'[n][k], k=0..127
    __shared__ __align__(16) ushort_t sOt[48 * 72];        //  6912 B: O[n][k],  k=0..63
    __shared__ __align__(16) ushort_t sFeat[DENSE ? 1 : 4][DENSE ? 16 : 16 * 136];
    __shared__ __align__(16) ushort_t sH2[4][16 * 88];     // 11264 B: h2 rows / logit stage
    // DENSE: ~35.6 KB -> 4 blocks/CU

    // ---- stage transposed weights (once per block) ----
    // sWt: coalesced float4 global reads (lanes cover consecutive n), 8/thread
    for (int t = threadIdx.x; t < 64 * 128 / 4; t += 256) {
        int k  = t >> 4;            // 0..127
        int n0 = (t & 15) * 4;      // 0..60
        float4 w4 = *(const float4*)(gw + k * C_CH + n0);
        float wv[4] = {w4.x, w4.y, w4.z, w4.w};
#pragma unroll
        for (int q = 0; q < 4; ++q) {
            float w = wv[q];
            if (k == n0 + q) w += 1.0f;          // residual folded in: W' = W + [I;0]
            sWt[(n0 + q) * 136 + k] = f2bu(w);
        }
    }
    for (int t = threadIdx.x; t < 48 * 64; t += 256) {
        int n = t >> 6, k = t & 63;
        float w = (n < NCLS) ? ow[k * NCLS + n] : 0.f;
        sOt[n * 72 + k] = f2bu(w);
    }
    __syncthreads();

    const int lane   = threadIdx.x & 63;
    const int wave   = threadIdx.x >> 6;
    const int lanelo = lane & 15;
    const int quad   = lane >> 4;

    float gbf[4];
#pragma unroll
    for (int nt = 0; nt < 4; ++nt) gbf[nt] = gb[nt * 16 + lanelo];
    float obf[3];
#pragma unroll
    for (int nt = 0; nt < 3; ++nt) {
        int n = nt * 16 + lanelo;
        obf[nt] = (n < NCLS) ? ob[n] : 0.f;
    }
    const bool ok2 = (lanelo < 8);   // n-tile 2 covers cols 32..47; valid n<40

    int gBeg, gEnd, gStep;
    if constexpr (DENSE) { gBeg = blockIdx.x * GPB; gEnd = gBeg + GPB; gStep = 1; }
    else                 { gBeg = blockIdx.x; gEnd = (N_NODES >> 6); gStep = gridDim.x; }

    // ---- DENSE: prefetch first group's A-fragments ----
    short8 afc[4];
    if constexpr (DENSE) {
        const int nb0 = gBeg * 64 + wave * 16;
#pragma unroll
        for (int s = 0; s < 4; ++s) {
            const ushort_t* tbl = (s < 2) ? hws : relws;
            afc[s] = *(const short8*)(tbl + ((size_t)(nb0 + lanelo) << 6)
                                      + (s & 1) * 32 + quad * 8);
        }
    }

    for (int g = gBeg; g < gEnd; g += gStep) {
        const int nb0 = g * 64 + wave * 16;
        ushort_t* h2w = &sH2[wave][0];

        // ---- proj: D[16x64] = feat[16x128] @ W' + gb ----
        floatx4 acc[4];
#pragma unroll
        for (int nt = 0; nt < 4; ++nt) acc[nt] = bcast4(gbf[nt]);

        if constexpr (DENSE) {
            // issue next group's A-frag loads FIRST: ~900cy HBM/L3 latency
            // hides under this group's MFMAs + head + softmax.
            short8 afn[4];
            const int gn  = (g + 1 < gEnd) ? g + 1 : g;   // clamp: harmless reload
            const int nbn = gn * 64 + wave * 16;
#pragma unroll
            for (int s = 0; s < 4; ++s) {
                const ushort_t* tbl = (s < 2) ? hws : relws;
                afn[s] = *(const short8*)(tbl + ((size_t)(nbn + lanelo) << 6)
                                          + (s & 1) * 32 + quad * 8);
            }
#pragma unroll
            for (int s = 0; s < 4; ++s) {
#pragma unroll
                for (int nt = 0; nt < 4; ++nt) {
                    short8 bf = *(const short8*)(sWt + (nt * 16 + lanelo) * 136 + s * 32 + quad * 8);
                    acc[nt] = __builtin_amdgcn_mfma_f32_16x16x32_bf16(afc[s], bf, acc[nt], 0, 0, 0);
                }
            }
#pragma unroll
            for (int s = 0; s < 4; ++s) afc[s] = afn[s];
        } else {
            ushort_t* feat = &sFeat[wave][0];
#pragma unroll
            for (int q = 0; q < 4; ++q) {
                int idxv = ldi(nbr, (long)nb0 * K_NBR + q * 64 + lane);
#pragma unroll
                for (int tt = 0; tt < 4; ++tt) {
                    int t = q * 4 + tt;
                    ushort_t hu = hws[(size_t)(nb0 + t) * C_CH + lane];
                    float hif = bu2f(hu);
                    float mx = -1e30f;
#pragma unroll
                    for (int k = 0; k < 16; ++k) {
                        int j = __shfl(idxv, tt * 16 + k, 64);
                        mx = fmaxf(mx, bu2f(hws[((size_t)(unsigned)j << 6) + lane]));
                    }
                    feat[t * 136 + lane]      = hu;
                    feat[t * 136 + 64 + lane] = f2bu(mx - hif);
                }
            }
            __syncthreads();
#pragma unroll
            for (int s = 0; s < 4; ++s) {
                short8 af = *(const short8*)(feat + lanelo * 136 + s * 32 + quad * 8);
#pragma unroll
                for (int nt = 0; nt < 4; ++nt) {
                    short8 bf = *(const short8*)(sWt + (nt * 16 + lanelo) * 136 + s * 32 + quad * 8);
                    acc[nt] = __builtin_amdgcn_mfma_f32_16x16x32_bf16(af, bf, acc[nt], 0, 0, 0);
                }
            }
        }

#pragma unroll
        for (int nt = 0; nt < 4; ++nt)
#pragma unroll
            for (int r = 0; r < 4; ++r)
                h2w[(quad * 4 + r) * 88 + nt * 16 + lanelo] = f2bu(acc[nt][r]);
        if constexpr (DENSE) { asm volatile("" ::: "memory"); }  // sH2 per-wave: order-only fence
        else                 { __syncthreads(); }

        // ---- head: L[16x48] = h2[16x64] @ O (+ ob) ----
        floatx4 accH[3];
#pragma unroll
        for (int nt = 0; nt < 3; ++nt) accH[nt] = bcast4(obf[nt]);
#pragma unroll
        for (int s = 0; s < 2; ++s) {
            short8 hf = *(const short8*)(h2w + lanelo * 88 + s * 32 + quad * 8);
#pragma unroll
            for (int nt = 0; nt < 3; ++nt) {
                short8 bf = *(const short8*)(sOt + (nt * 16 + lanelo) * 72 + s * 32 + quad * 8);
                accH[nt] = __builtin_amdgcn_mfma_f32_16x16x32_bf16(hf, bf, accH[nt], 0, 0, 0);
            }
        }
        if constexpr (DENSE) { asm volatile("" ::: "memory"); }  // h2 reads before fOut overwrite

        // ---- log-softmax per row; stage logits in LDS (reuse h2 region) ----
        float* fOut = (float*)h2w;
#pragma unroll
        for (int r = 0; r < 4; ++r) {
            float v0 = accH[0][r], v1 = accH[1][r];
            float v2 = ok2 ? accH[2][r] : -1e30f;
            float m = fmaxf(fmaxf(v0, v1), v2);
#pragma unroll
            for (int off = 1; off < 16; off <<= 1) m = fmaxf(m, __shfl_xor(m, off, 64));
            float s = __expf(v0 - m) + __expf(v1 - m) + (ok2 ? __expf(v2 - m) : 0.f);
#pragma unroll
            for (int off = 1; off < 16; off <<= 1) s += __shfl_xor(s, off, 64);
            float li = m + __logf(s);
            int rowbase = (quad * 4 + r) * NCLS;
            fOut[rowbase + lanelo]      = v0 - li;
            fOut[rowbase + 16 + lanelo] = v1 - li;
            if (ok2) fOut[rowbase + 32 + lanelo] = v2 - li;
        }
        if constexpr (DENSE) { asm volatile("" ::: "memory"); }  // fOut writes before readback
        else                 { __syncthreads(); }

        // ---- flat coalesced write: 640 consecutive floats per wave ----
        float* obase = out + (size_t)nb0 * NCLS;
#pragma unroll
        for (int k = 0; k < 10; ++k)
            obase[k * 64 + lane] = fOut[k * 64 + lane];
        if constexpr (DENSE) { asm volatile("" ::: "memory"); }  // fOut reads before next-iter h2 write
    }
}

extern "C" void kernel_launch(void* const* d_in, const int* in_sizes, int n_in,
                              void* d_out, int out_size, void* d_ws, size_t ws_size,
                              hipStream_t stream) {
    const float* x  = (const float*)d_in[0];
    const float* cw = (const float*)d_in[2];
    const float* cb = (const float*)d_in[3];
    const float* gw = (const float*)d_in[4];
    const float* gb = (const float*)d_in[5];
    const float* ow = (const float*)d_in[6];
    const float* ob = (const float*)d_in[7];
    float* out = (float*)d_out;

    int* flags = (int*)d_ws;
    ushort_t* hws   = (ushort_t*)((char*)d_ws + 1024);              // 32 MB
    ushort_t* relws = (ushort_t*)((char*)d_ws + 1024 + 33554432);   // 32 MB

    const bool split = (ws_size >= (size_t)(1024 + 2 * 33554432ULL));

    sniff_kernel<<<1, 64, 0, stream>>>(d_in[1], flags);
    cpe_kernel<<<(N_NODES / 4 * 16) / 256, 256, 0, stream>>>(x, cw, cb, hws);

    if (split) {
        // scalar-index gather: single dispatch, runtime int32/int64 branch
        gather_kernel<<<N_NODES / 16, 256, 0, stream>>>(
            flags, hws, d_in[1], relws);
        // dense MFMA pipeline: 1024 blocks x GPB=4 groups, staging amortized
        graph_head_kernel<true, int><<<(N_NODES / 64) / GPB, 256, 0, stream>>>(
            flags, hws, relws, (const int*)d_in[1], gw, gb, ow, ob, out);
    } else {
        // fallback: fused gather (round-10 path)
        graph_head_kernel<false, int><<<2048, 256, 0, stream>>>(
            flags, hws, relws, (const int*)d_in[1], gw, gb, ow, ob, out);
        graph_head_kernel<false, long long><<<2048, 256, 0, stream>>>(
            flags, hws, relws, (const long long*)d_in[1], gw, gb, ow, ob, out);
    }
}

// Round 3
// 214.643 us; speedup vs baseline: 1.3922x; 1.0946x over previous
//
#include <hip/hip_runtime.h>
#include <hip/hip_bf16.h>

#define N_NODES 262144
#define C_CH 64
#define K_NBR 16
#define NCLS 40

typedef unsigned short ushort_t;
typedef __attribute__((ext_vector_type(8))) short short8;
typedef __attribute__((ext_vector_type(4))) float floatx4;

__device__ __forceinline__ float bu2f(ushort_t u) {
    union { unsigned u32; float f; } v; v.u32 = ((unsigned)u) << 16; return v.f;
}
__device__ __forceinline__ ushort_t f2bu(float f) {
    union { float f; unsigned u; } v; v.f = f;
    unsigned r = v.u + 0x7FFFu + ((v.u >> 16) & 1u);
    return (ushort_t)(r >> 16);
}
__device__ __forceinline__ floatx4 bcast4(float g) {
    floatx4 v; v[0] = g; v[1] = g; v[2] = g; v[3] = g; return v;
}
__device__ __forceinline__ int ldi(const int* p, long i)       { return p[i]; }
__device__ __forceinline__ int ldi(const long long* p, long i) { return (int)p[i]; }

// ---------------- Kernel A: CPE depthwise conv3 + residual ------------------
// f32 x -> bf16 h table. One thread = 4 channels (float4) x 4 nodes.
// Block 0 wave 0 additionally runs the int64-sniffer (saves a dispatch).
__global__ void cpe_kernel(const float* __restrict__ x,
                           const float* __restrict__ cw,
                           const float* __restrict__ cb,
                           ushort_t* __restrict__ h,
                           const void* __restrict__ nbr,
                           int* __restrict__ flags) {
    if (blockIdx.x == 0 && threadIdx.x < 64) {   // whole wave 0: ballot is safe
        int lane = threadIdx.x;
        const int* ni = (const int*)nbr;
        bool zodd = (ni[2 * lane + 1] == 0);     // int64 high words all zero
        unsigned long long mz = __ballot(zodd);
        if (lane == 0) flags[1] = (mz == ~0ULL) ? 1 : 0;
    }
    int t  = blockIdx.x * 256 + threadIdx.x;   // [0, N/4 * 16)
    int ig = t >> 4;                           // node group (4 nodes)
    int cq = t & 15;                           // channel quad
    int i0 = ig << 2;
    int c0 = cq * 4;
    float w0[4], w1[4], w2[4], bb[4];
#pragma unroll
    for (int j = 0; j < 4; ++j) {
        w0[j] = cw[(c0 + j) * 3 + 0];
        w1[j] = cw[(c0 + j) * 3 + 1];
        w2[j] = cw[(c0 + j) * 3 + 2];
        bb[j] = cb[c0 + j];
    }
    float4 v[6];
#pragma unroll
    for (int r = 0; r < 6; ++r) {
        int i = i0 - 1 + r;
        if (i >= 0 && i < N_NODES) v[r] = *(const float4*)(x + (size_t)i * C_CH + c0);
        else                       v[r] = make_float4(0.f, 0.f, 0.f, 0.f);
    }
#pragma unroll
    for (int j = 0; j < 4; ++j) {
        float a[4] = {v[j].x, v[j].y, v[j].z, v[j].w};
        float b[4] = {v[j+1].x, v[j+1].y, v[j+1].z, v[j+1].w};
        float c[4] = {v[j+2].x, v[j+2].y, v[j+2].z, v[j+2].w};
        unsigned p0 = 0, p1 = 0;
#pragma unroll
        for (int q = 0; q < 4; ++q) {
            float r = b[q] + bb[q];
            r = fmaf(a[q], w0[q], r);
            r = fmaf(b[q], w1[q], r);
            r = fmaf(c[q], w2[q], r);
            unsigned u = (unsigned)f2bu(r);
            if (q < 2) p0 |= u << (q * 16);
            else       p1 |= u << ((q - 2) * 16);
        }
        *(uint2*)(h + (size_t)(i0 + j) * C_CH + c0) = make_uint2(p0, p1);
    }
}

// ---------------- FUSED: gather + max-rel + proj + head + logsoftmax --------
// One wave owns 16 nodes end-to-end. Gather phase: scalar (s_load) neighbor
// indices, 16 independent 128B row loads per node, fmax tree, feat staged in
// the wave's PRIVATE LDS slice. MFMA phase: proj (feat@W') -> h2 overlay ->
// head (h2@O) -> softmax -> out. Zero barriers after weight staging, so the
// 16 resident waves/CU freely interleave memory-phase and MFMA-phase work,
// hiding the random-gather L2-miss latency under compute. Removes the rel
// intermediate (32MB write + 32MB read) and one dispatch vs the split form.
// LDS overlay (feat -> h2 -> fOut) is ordered by dataflow + per-wave
// in-order DS + compiler clobbers (pattern validated in prior rounds).
template <typename IT>
__device__ __forceinline__ void fused_body(const ushort_t* __restrict__ hws,
                                           const IT* __restrict__ nbr,
                                           const float* __restrict__ gb,
                                           const float* __restrict__ ob,
                                           float* __restrict__ out,
                                           const ushort_t* sWt,
                                           const ushort_t* sOt,
                                           ushort_t* feat,
                                           int lane) {
    const int lanelo = lane & 15;
    const int quad   = lane >> 4;
    float gbf[4];
#pragma unroll
    for (int nt = 0; nt < 4; ++nt) gbf[nt] = gb[nt * 16 + lanelo];
    float obf[3];
#pragma unroll
    for (int nt = 0; nt < 3; ++nt) {
        int n = nt * 16 + lanelo;
        obf[nt] = (n < NCLS) ? ob[n] : 0.f;
    }
    const bool ok2 = (lanelo < 8);   // n-tile 2 covers cols 32..47; valid n<40

    const int nTasks = N_NODES / 16;                   // 16384 wave-tasks
    const int wslots = gridDim.x * 8;                  // 8 waves per block
    const int wv     = threadIdx.x >> 6;

    for (int task0 = blockIdx.x * 8 + wv; task0 < nTasks; task0 += wslots) {
        const int task = __builtin_amdgcn_readfirstlane(task0);  // force SGPR
        const int nb0  = task * 16;
        const IT* nrow = nbr + (size_t)nb0 * K_NBR;              // wave-uniform

        // ---- gather + max-rel: 16 nodes, feat[t][0:64]=h, [64:128]=rel ----
        for (int t = 0; t < 16; ++t) {
            float v[16];
#pragma unroll
            for (int k = 0; k < 16; ++k) {
                int idx = (int)nrow[t * K_NBR + k];              // s_load batch
                v[k] = bu2f(hws[((size_t)(unsigned)idx << 6) + lane]);
            }
#pragma unroll
            for (int s = 8; s; s >>= 1)                          // fmax tree
#pragma unroll
                for (int k = 0; k < s; ++k)
                    v[k] = fmaxf(v[k], v[k + s]);
            ushort_t hu = hws[((size_t)(unsigned)(nb0 + t) << 6) + lane];
            feat[t * 136 + lane]      = hu;
            feat[t * 136 + 64 + lane] = f2bu(v[0] - bu2f(hu));
        }
        asm volatile("" ::: "memory");   // feat writes before A-frag reads

        // ---- proj: D[16x64] = feat[16x128] @ W' + gb ----
        floatx4 acc[4];
#pragma unroll
        for (int nt = 0; nt < 4; ++nt) acc[nt] = bcast4(gbf[nt]);
#pragma unroll
        for (int s = 0; s < 4; ++s) {
            short8 af = *(const short8*)(feat + lanelo * 136 + s * 32 + quad * 8);
#pragma unroll
            for (int nt = 0; nt < 4; ++nt) {
                short8 bf = *(const short8*)(sWt + (nt * 16 + lanelo) * 136 + s * 32 + quad * 8);
                acc[nt] = __builtin_amdgcn_mfma_f32_16x16x32_bf16(af, bf, acc[nt], 0, 0, 0);
            }
        }

        // ---- h2 overlays feat (feat dead after proj; dataflow-ordered) ----
        ushort_t* h2w = feat;
#pragma unroll
        for (int nt = 0; nt < 4; ++nt)
#pragma unroll
            for (int r = 0; r < 4; ++r)
                h2w[(quad * 4 + r) * 88 + nt * 16 + lanelo] = f2bu(acc[nt][r]);
        asm volatile("" ::: "memory");

        // ---- head: L[16x48] = h2[16x64] @ O (+ ob) ----
        floatx4 accH[3];
#pragma unroll
        for (int nt = 0; nt < 3; ++nt) accH[nt] = bcast4(obf[nt]);
#pragma unroll
        for (int s = 0; s < 2; ++s) {
            short8 hf = *(const short8*)(h2w + lanelo * 88 + s * 32 + quad * 8);
#pragma unroll
            for (int nt = 0; nt < 3; ++nt) {
                short8 bf = *(const short8*)(sOt + (nt * 16 + lanelo) * 72 + s * 32 + quad * 8);
                accH[nt] = __builtin_amdgcn_mfma_f32_16x16x32_bf16(hf, bf, accH[nt], 0, 0, 0);
            }
        }
        asm volatile("" ::: "memory");   // h2 reads before fOut overwrite

        // ---- log-softmax per row; logits staged in the same LDS slice ----
        float* fOut = (float*)feat;
#pragma unroll
        for (int r = 0; r < 4; ++r) {
            float v0 = accH[0][r], v1 = accH[1][r];
            float v2 = ok2 ? accH[2][r] : -1e30f;
            float m = fmaxf(fmaxf(v0, v1), v2);
#pragma unroll
            for (int off = 1; off < 16; off <<= 1) m = fmaxf(m, __shfl_xor(m, off, 64));
            float s = __expf(v0 - m) + __expf(v1 - m) + (ok2 ? __expf(v2 - m) : 0.f);
#pragma unroll
            for (int off = 1; off < 16; off <<= 1) s += __shfl_xor(s, off, 64);
            float li = m + __logf(s);
            int rowbase = (quad * 4 + r) * NCLS;
            fOut[rowbase + lanelo]      = v0 - li;
            fOut[rowbase + 16 + lanelo] = v1 - li;
            if (ok2) fOut[rowbase + 32 + lanelo] = v2 - li;
        }
        asm volatile("" ::: "memory");   // fOut writes before readback

        // ---- flat coalesced write: 640 consecutive floats per wave ----
        float* obase = out + (size_t)nb0 * NCLS;
#pragma unroll
        for (int k = 0; k < 10; ++k)
            obase[k * 64 + lane] = fOut[k * 64 + lane];
        asm volatile("" ::: "memory");   // fOut reads before next-task feat
    }
}

__global__ void __launch_bounds__(512, 4)
fused_kernel(const int* __restrict__ flags,
             const ushort_t* __restrict__ hws,
             const void* __restrict__ nbrv,
             const float* __restrict__ gw,
             const float* __restrict__ gb,
             const float* __restrict__ ow,
             const float* __restrict__ ob,
             float* __restrict__ out) {
    __shared__ __align__(16) ushort_t sWt[64 * 136];   // 17408 B: W'[n][k]
    __shared__ __align__(16) ushort_t sOt[48 * 72];    //  6912 B: O[n][k]
    __shared__ __align__(16) ushort_t sFeatU[8][2176]; // 34816 B: per-wave slice
    // total 59136 B -> 2 blocks/CU = 16 waves/CU

    // ---- stage transposed weights (once per block, coalesced float4) ----
    for (int t = threadIdx.x; t < 64 * 128 / 4; t += 512) {
        int k  = t >> 4;            // 0..127
        int n0 = (t & 15) * 4;      // 0..60
        float4 w4 = *(const float4*)(gw + k * C_CH + n0);
        float wv4[4] = {w4.x, w4.y, w4.z, w4.w};
#pragma unroll
        for (int q = 0; q < 4; ++q) {
            float w = wv4[q];
            if (k == n0 + q) w += 1.0f;          // residual folded: W' = W + [I;0]
            sWt[(n0 + q) * 136 + k] = f2bu(w);
        }
    }
    for (int t = threadIdx.x; t < 48 * 64; t += 512) {
        int n = t >> 6, k = t & 63;
        float w = (n < NCLS) ? ow[k * NCLS + n] : 0.f;
        sOt[n * 72 + k] = f2bu(w);
    }
    __syncthreads();   // the ONLY block-wide barrier

    const int lane = threadIdx.x & 63;
    const int wv   = __builtin_amdgcn_readfirstlane(threadIdx.x >> 6);
    ushort_t* feat = &sFeatU[wv][0];

    if (flags[1]) fused_body<long long>(hws, (const long long*)nbrv, gb, ob, out, sWt, sOt, feat, lane);
    else          fused_body<int>      (hws, (const int*)nbrv,       gb, ob, out, sWt, sOt, feat, lane);
}

// ---------------- Fallback: fused r10 path (small workspace) ----------------
template <typename IT>
__global__ void __launch_bounds__(256, 4)
graph_head_kernel(const int* __restrict__ flags,
                  const ushort_t* __restrict__ hws,
                  const IT* __restrict__ nbr,
                  const float* __restrict__ gw,
                  const float* __restrict__ gb,
                  const float* __restrict__ ow,
                  const float* __restrict__ ob,
                  float* __restrict__ out) {
    if ((flags[1] != 0) != (sizeof(IT) == 8)) return;

    __shared__ __align__(16) ushort_t sWt[64 * 136];
    __shared__ __align__(16) ushort_t sOt[48 * 72];
    __shared__ __align__(16) ushort_t sFeat[4][16 * 136];
    __shared__ __align__(16) ushort_t sH2[4][16 * 88];

    for (int t = threadIdx.x; t < 64 * 128 / 4; t += 256) {
        int k  = t >> 4;
        int n0 = (t & 15) * 4;
        float4 w4 = *(const float4*)(gw + k * C_CH + n0);
        float wv4[4] = {w4.x, w4.y, w4.z, w4.w};
#pragma unroll
        for (int q = 0; q < 4; ++q) {
            float w = wv4[q];
            if (k == n0 + q) w += 1.0f;
            sWt[(n0 + q) * 136 + k] = f2bu(w);
        }
    }
    for (int t = threadIdx.x; t < 48 * 64; t += 256) {
        int n = t >> 6, k = t & 63;
        float w = (n < NCLS) ? ow[k * NCLS + n] : 0.f;
        sOt[n * 72 + k] = f2bu(w);
    }
    __syncthreads();

    const int lane   = threadIdx.x & 63;
    const int wave   = threadIdx.x >> 6;
    const int lanelo = lane & 15;
    const int quad   = lane >> 4;

    float gbf[4];
#pragma unroll
    for (int nt = 0; nt < 4; ++nt) gbf[nt] = gb[nt * 16 + lanelo];
    float obf[3];
#pragma unroll
    for (int nt = 0; nt < 3; ++nt) {
        int n = nt * 16 + lanelo;
        obf[nt] = (n < NCLS) ? ob[n] : 0.f;
    }
    const bool ok2 = (lanelo < 8);

    for (int g = blockIdx.x; g < (N_NODES >> 6); g += gridDim.x) {
        const int nb0 = g * 64 + wave * 16;
        ushort_t* h2w = &sH2[wave][0];
        ushort_t* feat = &sFeat[wave][0];

        floatx4 acc[4];
#pragma unroll
        for (int nt = 0; nt < 4; ++nt) acc[nt] = bcast4(gbf[nt]);

#pragma unroll
        for (int q = 0; q < 4; ++q) {
            int idxv = ldi(nbr, (long)nb0 * K_NBR + q * 64 + lane);
#pragma unroll
            for (int tt = 0; tt < 4; ++tt) {
                int t = q * 4 + tt;
                ushort_t hu = hws[(size_t)(nb0 + t) * C_CH + lane];
                float hif = bu2f(hu);
                float mx = -1e30f;
#pragma unroll
                for (int k = 0; k < 16; ++k) {
                    int j = __shfl(idxv, tt * 16 + k, 64);
                    mx = fmaxf(mx, bu2f(hws[((size_t)(unsigned)j << 6) + lane]));
                }
                feat[t * 136 + lane]      = hu;
                feat[t * 136 + 64 + lane] = f2bu(mx - hif);
            }
        }
        __syncthreads();
#pragma unroll
        for (int s = 0; s < 4; ++s) {
            short8 af = *(const short8*)(feat + lanelo * 136 + s * 32 + quad * 8);
#pragma unroll
            for (int nt = 0; nt < 4; ++nt) {
                short8 bf = *(const short8*)(sWt + (nt * 16 + lanelo) * 136 + s * 32 + quad * 8);
                acc[nt] = __builtin_amdgcn_mfma_f32_16x16x32_bf16(af, bf, acc[nt], 0, 0, 0);
            }
        }

#pragma unroll
        for (int nt = 0; nt < 4; ++nt)
#pragma unroll
            for (int r = 0; r < 4; ++r)
                h2w[(quad * 4 + r) * 88 + nt * 16 + lanelo] = f2bu(acc[nt][r]);
        __syncthreads();

        floatx4 accH[3];
#pragma unroll
        for (int nt = 0; nt < 3; ++nt) accH[nt] = bcast4(obf[nt]);
#pragma unroll
        for (int s = 0; s < 2; ++s) {
            short8 hf = *(const short8*)(h2w + lanelo * 88 + s * 32 + quad * 8);
#pragma unroll
            for (int nt = 0; nt < 3; ++nt) {
                short8 bf = *(const short8*)(sOt + (nt * 16 + lanelo) * 72 + s * 32 + quad * 8);
                accH[nt] = __builtin_amdgcn_mfma_f32_16x16x32_bf16(hf, bf, accH[nt], 0, 0, 0);
            }
        }

        float* fOut = (float*)h2w;
#pragma unroll
        for (int r = 0; r < 4; ++r) {
            float v0 = accH[0][r], v1 = accH[1][r];
            float v2 = ok2 ? accH[2][r] : -1e30f;
            float m = fmaxf(fmaxf(v0, v1), v2);
#pragma unroll
            for (int off = 1; off < 16; off <<= 1) m = fmaxf(m, __shfl_xor(m, off, 64));
            float s = __expf(v0 - m) + __expf(v1 - m) + (ok2 ? __expf(v2 - m) : 0.f);
#pragma unroll
            for (int off = 1; off < 16; off <<= 1) s += __shfl_xor(s, off, 64);
            float li = m + __logf(s);
            int rowbase = (quad * 4 + r) * NCLS;
            fOut[rowbase + lanelo]      = v0 - li;
            fOut[rowbase + 16 + lanelo] = v1 - li;
            if (ok2) fOut[rowbase + 32 + lanelo] = v2 - li;
        }
        __syncthreads();

        float* obase = out + (size_t)nb0 * NCLS;
#pragma unroll
        for (int k = 0; k < 10; ++k)
            obase[k * 64 + lane] = fOut[k * 64 + lane];
    }
}

extern "C" void kernel_launch(void* const* d_in, const int* in_sizes, int n_in,
                              void* d_out, int out_size, void* d_ws, size_t ws_size,
                              hipStream_t stream) {
    const float* x  = (const float*)d_in[0];
    const float* cw = (const float*)d_in[2];
    const float* cb = (const float*)d_in[3];
    const float* gw = (const float*)d_in[4];
    const float* gb = (const float*)d_in[5];
    const float* ow = (const float*)d_in[6];
    const float* ob = (const float*)d_in[7];
    float* out = (float*)d_out;

    int* flags = (int*)d_ws;
    ushort_t* hws = (ushort_t*)((char*)d_ws + 1024);   // 32 MB bf16 h table

    const bool fits = (ws_size >= (size_t)(1024 + 33554432ULL));

    // cpe (+ inlined sniffer, block 0)
    cpe_kernel<<<(N_NODES / 4 * 16) / 256, 256, 0, stream>>>(x, cw, cb, hws,
                                                             d_in[1], flags);
    if (fits) {
        // fused gather+proj+head: 512 blocks x 8 waves, 4 tasks/wave
        fused_kernel<<<512, 512, 0, stream>>>(flags, hws, d_in[1],
                                              gw, gb, ow, ob, out);
    } else {
        graph_head_kernel<int><<<2048, 256, 0, stream>>>(
            flags, hws, (const int*)d_in[1], gw, gb, ow, ob, out);
        graph_head_kernel<long long><<<2048, 256, 0, stream>>>(
            flags, hws, (const long long*)d_in[1], gw, gb, ow, ob, out);
    }
}